// Round 12
// baseline (65.277 us; speedup 1.0000x reference)
//
#include <hip/hip_runtime.h>
#include <stdint.h>

typedef short bf16x8 __attribute__((ext_vector_type(8)));
typedef float f32x4 __attribute__((ext_vector_type(4)));

#define NCI 128
#define NCO 128
#define HIN 64
#define HP  66
#define NB  8

__device__ __forceinline__ unsigned short f32_to_bf16(float f) {
    union { float f; uint32_t u; } v; v.f = f;
    return (unsigned short)((v.u + 0x7FFFu + ((v.u >> 16) & 1u)) >> 16);
}

// Effective 2x2-tap weight for parity (py,px), tap (ty,tx)
__device__ __forceinline__ float weff_sum(const float* wp, int py, int px, int ty, int tx) {
    float s = 0.f;
    #pragma unroll
    for (int ky = 0; ky < 3; ++ky) {
        bool iy = (py == 0) ? (ty == 0 ? (ky == 0) : (ky >= 1))
                            : (ty == 0 ? (ky <= 1) : (ky == 2));
        if (!iy) continue;
        #pragma unroll
        for (int kx = 0; kx < 3; ++kx) {
            bool ix = (px == 0) ? (tx == 0 ? (kx == 0) : (kx >= 1))
                                : (tx == 0 ? (kx <= 1) : (kx == 2));
            if (ix) s += wp[ky * 3 + kx];
        }
    }
    return s;
}

// ---- fused prologue ----
// blocks [0,1024): Weff -> Aw6, 32co-band fragment-major:
//   offset = ((par*16+kt)*4 + cob)*1024 + f*512 + pl*128 + rl*8 + e
//   content = Weff[par][co = cob*32 + f*16 + rl][k = kt*32 + pl*8 + e]  (512 KB)
// blocks [1024,1552): x -> xq [8][4][66][66][32] bf16 (ci-chunked NHWC, halo incl).
__global__ __launch_bounds__(256) void prep_kernel(
        const float* __restrict__ W, const float* __restrict__ x,
        unsigned short* __restrict__ Aw6, unsigned short* __restrict__ xq) {
    if (blockIdx.x < 1024) {
        int idx = blockIdx.x * 256 + threadIdx.x;     // 262144 total
        int e   = idx & 7;
        int rl  = (idx >> 3) & 15;
        int pl  = (idx >> 7) & 3;
        int f   = (idx >> 9) & 1;
        int cob = (idx >> 10) & 3;
        int kt  = (idx >> 12) & 15;
        int par = idx >> 16;
        int co = cob * 32 + f * 16 + rl;
        int k  = kt * 32 + pl * 8 + e;
        int tap = k >> 7, ci = k & 127;
        Aw6[idx] = f32_to_bf16(weff_sum(W + (co * NCI + ci) * 9,
                                        par >> 1, par & 1, tap >> 1, tap & 1));
    } else {
        const int bb = blockIdx.x - 1024;             // 528 blocks
        const int b = bb / HP, hp = bb % HP;
        const int t = threadIdx.x;
        if (hp == 0 || hp == HP - 1) {
            bf16x8 z = (bf16x8){0, 0, 0, 0, 0, 0, 0, 0};
            for (int i = t; i < 4 * HP * 4; i += 256) {
                int g = i / (HP * 4), rem = i % (HP * 4);
                unsigned short* dst = xq +
                    ((((size_t)(b * 4 + g) * HP + hp) * HP) << 5) + rem * 8;
                *(bf16x8*)dst = z;
            }
            return;
        }
        const int h = hp - 1;
        if (t < 32) {                                  // column halo wp = 0, 65
            bf16x8 z = (bf16x8){0, 0, 0, 0, 0, 0, 0, 0};
            int g = t >> 3, wpc = ((t >> 2) & 1) * (HP - 1), q = t & 3;
            unsigned short* dst = xq +
                ((((size_t)(b * 4 + g) * HP + hp) * HP + wpc) << 5) + q * 8;
            *(bf16x8*)dst = z;
        }
        const int w = t & 63, g = t >> 6;
        const float* src = x + ((size_t)(b * NCI + g * 32) * (HIN * HIN)) + h * HIN + w;
        unsigned short* dst = xq +
            ((((size_t)(b * 4 + g) * HP + hp) * HP + (w + 1)) << 5);
        #pragma unroll
        for (int q = 0; q < 4; ++q) {
            bf16x8 v;
            #pragma unroll
            for (int j = 0; j < 8; ++j)
                v[j] = (short)f32_to_bf16(src[(size_t)(q * 8 + j) * (HIN * HIN)]);
            *(bf16x8*)(dst + q * 8) = v;
        }
    }
}

// Main GEMM: NO LDS, NO barriers, 4 waves/SIMD occupancy tier (~100 regs).
// Wave = 32co x 64sp for one (py,px). A and B stream global(L2)->reg as
// contiguous 1KB wave-lines, 2-kt-ahead named ping-pong prefetch (compiler
// emits counted vmcnt). Output via nontemporal stores (no L2 pollution).
__global__ __launch_bounds__(256, 4) void upconv13_kernel(
        const unsigned short* __restrict__ xq, const unsigned short* __restrict__ Aw6,
        const float* __restrict__ bv, float* __restrict__ out) {
    const int d = blockIdx.x;                    // 2048 blocks
    const int cob2 = d & 1;
    const int dd = d >> 1;                       // 1024
    const int dsw = (dd & 7) * 128 + (dd >> 3);  // bijective XCD swizzle
    const int py = dsw & 1;
    const int t = dsw >> 1;
    const int bi = t >> 6, oy0 = t & 63;
    const int tid = threadIdx.x, lane = tid & 63, wv = tid >> 6;
    const int pxw = wv & 1, cobL = wv >> 1;
    const int cob = cob2 * 2 + cobL;
    const int rl = lane & 15, pl = lane >> 4;
    const int par = py * 2 + pxw;

    // A: per-wave contiguous 1KB lines; kt stride = 4096 shorts
    const unsigned short* Ab = Aw6 + (((par * 16 * 4) + cob) << 10) + lane * 8;
    // B: per-lane offset inside a contiguous 1KB frag line
    const char* xqb = (const char*)xq + (((size_t)bi * 4 * HP * HP) << 6);
    const int blane = rl * 64 + pl * 16;

    f32x4 acc[2][4];
    #pragma unroll
    for (int i = 0; i < 2; ++i)
        #pragma unroll
        for (int j = 0; j < 4; ++j)
            acc[i][j] = (f32x4){0.f, 0.f, 0.f, 0.f};

    bf16x8 A0[2], A1[2], B0[4], B1[4];

    auto loadA = [&](bf16x8* Ad, int kt) {
        const unsigned short* p = Ab + (kt << 12);
        Ad[0] = *(const bf16x8*)p;
        Ad[1] = *(const bf16x8*)(p + 512);
    };
    auto loadB = [&](bf16x8* Bd, int kt) {
        const int row = oy0 + py + (kt >> 3);
        const int g = kt & 3;
        const int cb = pxw + ((kt >> 2) & 1);
        const char* base = xqb + (((g * HP + row) * HP + cb) << 6) + blane;
        #pragma unroll
        for (int fn = 0; fn < 4; ++fn)
            Bd[fn] = *(const bf16x8*)(base + fn * 1024);
    };

    // 2-deep prologue: 12 loads in flight
    loadB(B0, 0);
    loadA(A0, 0);
    loadB(B1, 1);
    loadA(A1, 1);

    #pragma unroll
    for (int kp = 0; kp < 16; ++kp) {
        bf16x8* Ac = (kp & 1) ? A1 : A0;
        bf16x8* Bc = (kp & 1) ? B1 : B0;
        __builtin_amdgcn_s_setprio(1);
        #pragma unroll
        for (int fn = 0; fn < 4; ++fn)
            #pragma unroll
            for (int fm = 0; fm < 2; ++fm)
                acc[fm][fn] = __builtin_amdgcn_mfma_f32_16x16x32_bf16(
                    Ac[fm], Bc[fn], acc[fm][fn], 0, 0, 0);
        __builtin_amdgcn_s_setprio(0);
        if (kp + 2 < 16) {          // prefetch kt+2 into the buffers just consumed
            loadB(Bc, kp + 2);
            loadA(Ac, kp + 2);
        }
    }

    // epilogue: nontemporal strided stores (stride 8B -> 8 lines/instr; the
    // partner pxw-wave in the same block fills complementary 4B slots).
    const int yy = 2 * oy0 + py;
    float* ob = out + (((size_t)(bi * NCO + cob * 32 + pl * 4)) << 14)
                    + yy * 128 + 2 * rl + pxw;
    #pragma unroll
    for (int fm = 0; fm < 2; ++fm) {
        #pragma unroll
        for (int j = 0; j < 4; ++j) {
            const float bb = bv[cob * 32 + fm * 16 + pl * 4 + j];
            float* o2 = ob + (((size_t)(fm * 16 + j)) << 14);
            #pragma unroll
            for (int fn = 0; fn < 4; ++fn)
                __builtin_nontemporal_store(acc[fm][fn][j] + bb, o2 + fn * 32);
        }
    }
}

// -------- fallback (ws too small for xq): flat Weff + direct-x kernel --------
__global__ void weff_flat_kernel(const float* __restrict__ W,
                                 unsigned short* __restrict__ Aw) {
    int idx = blockIdx.x * 256 + threadIdx.x;   // Aw[par][co][512]
    int par = idx >> 16;
    int co  = (idx >> 9) & 127;
    int k   = idx & 511;
    int tap = k >> 7, ci = k & 127;
    Aw[idx] = f32_to_bf16(weff_sum(W + (co * NCI + ci) * 9,
                                   par >> 1, par & 1, tap >> 1, tap & 1));
}

__global__ __launch_bounds__(256) void upconv_fb_kernel(
        const float* __restrict__ x, const unsigned short* __restrict__ Aw,
        const float* __restrict__ bv, float* __restrict__ out) {
    __shared__ __align__(16) unsigned short A_lds[128 * 32];
    __shared__ __align__(16) unsigned short B_lds[128 * 32];
    const int par = blockIdx.y, py = par >> 1, px = par & 1;
    const int s0 = blockIdx.x * 128;
    const int bimg = s0 >> 12;
    const int oy0 = (s0 >> 6) & 63;
    const int tid = threadIdx.x;
    const int lane = tid & 63, wave = tid >> 6;
    const int wm = wave >> 1, wn = wave & 1;
    const float* xb = x + bimg * (NCI * HIN * HIN);
    f32x4 acc[4][4];
    #pragma unroll
    for (int i = 0; i < 4; ++i)
        #pragma unroll
        for (int j = 0; j < 4; ++j)
            acc[i][j] = (f32x4){0.f, 0.f, 0.f, 0.f};
    for (int kt = 0; kt < 16; ++kt) {
        const int tap = kt >> 2, ci0 = (kt & 3) * 32;
        const int ty = tap >> 1, tx = tap & 1;
        #pragma unroll
        for (int i = 0; i < 2; ++i) {
            int c = i * 256 + tid;
            *(bf16x8*)(&A_lds[c * 8]) = *(const bf16x8*)(Aw +
                ((par * 128 + (c >> 2)) * 512 + kt * 32 + (c & 3) * 8));
        }
        #pragma unroll
        for (int i = 0; i < 2; ++i) {
            int tsk = i * 256 + tid;
            int n = tsk & 127, kg = tsk >> 7;
            int r = n >> 6, ox = n & 63;
            int row = oy0 + r - 1 + py + ty;
            int col = ox - 1 + px + tx;
            bool ok = (row >= 0) & (row < HIN) & (col >= 0) & (col < HIN);
            const float* xp = xb + (((ci0 + kg * 8) * HIN + row) * HIN + col);
            bf16x8 v;
            #pragma unroll
            for (int q = 0; q < 8; ++q) {
                float f = ok ? xp[q * (HIN * HIN)] : 0.f;
                v[q] = (short)f32_to_bf16(f);
            }
            *(bf16x8*)(&B_lds[n * 32 + kg * 8]) = v;
        }
        __syncthreads();
        const int seg = (lane >> 4) * 8, rl2 = lane & 15;
        bf16x8 af[4], bfr[4];
        #pragma unroll
        for (int f = 0; f < 4; ++f)
            af[f] = *(const bf16x8*)(&A_lds[(wm * 64 + f * 16 + rl2) * 32 + seg]);
        #pragma unroll
        for (int f = 0; f < 4; ++f)
            bfr[f] = *(const bf16x8*)(&B_lds[(wn * 64 + f * 16 + rl2) * 32 + seg]);
        #pragma unroll
        for (int fm = 0; fm < 4; ++fm)
            #pragma unroll
            for (int fn = 0; fn < 4; ++fn)
                acc[fm][fn] = __builtin_amdgcn_mfma_f32_16x16x32_bf16(
                    af[fm], bfr[fn], acc[fm][fn], 0, 0, 0);
        __syncthreads();
    }
    #pragma unroll
    for (int fm = 0; fm < 4; ++fm) {
        const int co_b = wm * 64 + fm * 16 + (lane >> 4) * 4;
        float bias4[4];
        #pragma unroll
        for (int j = 0; j < 4; ++j) bias4[j] = bv[co_b + j];
        #pragma unroll
        for (int fn = 0; fn < 4; ++fn) {
            int n = wn * 64 + fn * 16 + (lane & 15);
            int s = s0 + n;
            int ox = s & 63, oy = (s >> 6) & 63, bi2 = s >> 12;
            int yy = 2 * oy + py, xx = 2 * ox + px;
            float* op = out + ((size_t)bi2 * 128 * 128 * 128) + (size_t)yy * 128 + xx;
            #pragma unroll
            for (int j = 0; j < 4; ++j)
                op[(size_t)(co_b + j) * (128 * 128)] = acc[fm][fn][j] + bias4[j];
        }
    }
}

extern "C" void kernel_launch(void* const* d_in, const int* in_sizes, int n_in,
                              void* d_out, int out_size, void* d_ws, size_t ws_size,
                              hipStream_t stream) {
    const float* x  = (const float*)d_in[0];
    const float* W  = (const float*)d_in[1];
    const float* bv = (const float*)d_in[2];
    float* out = (float*)d_out;
    unsigned short* Aw = (unsigned short*)d_ws;               // 512 KB
    const size_t aw_bytes = (size_t)4 * 16 * 4 * 1024 * sizeof(unsigned short);
    const size_t xq_bytes = (size_t)NB * 4 * HP * HP * 32 * sizeof(unsigned short);

    if (ws_size >= aw_bytes + xq_bytes) {
        unsigned short* xq = (unsigned short*)((char*)d_ws + aw_bytes);
        prep_kernel<<<1024 + NB * HP, 256, 0, stream>>>(W, x, Aw, xq);
        upconv13_kernel<<<2048, 256, 0, stream>>>(xq, Aw, bv, out);
    } else {
        weff_flat_kernel<<<1024, 256, 0, stream>>>(W, Aw);
        upconv_fb_kernel<<<dim3(256, 4), 256, 0, stream>>>(x, Aw, bv, out);
    }
}

// Round 13
// 48.081 us; speedup vs baseline: 1.3576x; 1.3576x over previous
//
#include <hip/hip_runtime.h>
#include <stdint.h>

typedef short bf16x8 __attribute__((ext_vector_type(8)));
typedef float f32x4 __attribute__((ext_vector_type(4)));

#define NCI 128
#define NCO 128
#define HIN 64
#define NB  8

__device__ __forceinline__ unsigned short f32_to_bf16(float f) {
    union { float f; uint32_t u; } v; v.f = f;
    return (unsigned short)((v.u + 0x7FFFu + ((v.u >> 16) & 1u)) >> 16);
}

// Effective 2x2-tap weight for parity (py,px), tap (ty,tx)
__device__ __forceinline__ float weff_sum(const float* wp, int py, int px, int ty, int tx) {
    float s = 0.f;
    #pragma unroll
    for (int ky = 0; ky < 3; ++ky) {
        bool iy = (py == 0) ? (ty == 0 ? (ky == 0) : (ky >= 1))
                            : (ty == 0 ? (ky <= 1) : (ky == 2));
        if (!iy) continue;
        #pragma unroll
        for (int kx = 0; kx < 3; ++kx) {
            bool ix = (px == 0) ? (tx == 0 ? (kx == 0) : (kx >= 1))
                                : (tx == 0 ? (kx <= 1) : (kx == 2));
            if (ix) s += wp[ky * 3 + kx];
        }
    }
    return s;
}

// Weff -> Aw6, 32co-band fragment-major (same layout as round 12):
//   offset = ((par*16+kt)*4 + cob)*1024 + f*512 + pl*128 + rl*8 + e
//   content = Weff[par][co = cob*32 + f*16 + rl][k = kt*32 + pl*8 + e]  (512 KB)
__global__ __launch_bounds__(256) void weff6_kernel(
        const float* __restrict__ W, unsigned short* __restrict__ Aw6) {
    int idx = blockIdx.x * 256 + threadIdx.x;     // 262144 total
    int e   = idx & 7;
    int rl  = (idx >> 3) & 15;
    int pl  = (idx >> 7) & 3;
    int f   = (idx >> 9) & 1;
    int cob = (idx >> 10) & 3;
    int kt  = (idx >> 12) & 15;
    int par = idx >> 16;
    int co = cob * 32 + f * 16 + rl;
    int k  = kt * 32 + pl * 8 + e;
    int tap = k >> 7, ci = k & 127;
    Aw6[idx] = f32_to_bf16(weff_sum(W + (co * NCI + ci) * 9,
                                    par >> 1, par & 1, tap >> 1, tap & 1));
}

// Fused upsample-conv: block = (bi, oy0, py). Stages 2 input rows (+zero col
// halo) from x f32 -> bf16 swizzled LDS tile (33.8 KB) once; barrier-free
// K-loop with A 3-deep global(L2)->reg ping-pong and B from LDS; LDS-merged
// coalesced epilogue. 512 thr = 8 waves: pxw(2) x cob(4); wave = 32co x 64sp.
__global__ __launch_bounds__(512, 4) void upconv14_kernel(
        const float* __restrict__ x, const unsigned short* __restrict__ Aw6,
        const float* __restrict__ bv, float* __restrict__ out) {
    // LDS: 2 rows x 66 cols x 16 ci-chunks x 16B = 33792 B; chunk q stored at
    // q ^ (c & 15)  (bank swizzle). Epilogue overlays as float[64][132].
    __shared__ __align__(16) unsigned short smem[16896];
    const int d = blockIdx.x;                 // 1024 blocks
    const int bi = d & 7;                     // XCD-local image
    const int py = (d >> 3) & 1;
    const int oy0 = d >> 4;                   // 0..63
    const int tid = threadIdx.x, lane = tid & 63, wv = tid >> 6;
    const int pxw = wv & 1, cob = wv >> 1;
    const int rl = lane & 15, pl = lane >> 4;
    const int par = py * 2 + pxw;

    // ---- zero col-halo cells c = 0, 65 (input cols -1, 64) ----
    if (tid < 64) {
        int r = tid >> 5, cz = ((tid >> 4) & 1) * 65, q = tid & 15;
        *(bf16x8*)&smem[((r * 66 + cz) * 16 + q) * 8] = (bf16x8){0,0,0,0,0,0,0,0};
    }
    // ---- stage interior: 32 tasks (r x ci-octet), 4 per wave; lane = w ----
    #pragma unroll
    for (int i = 0; i < 4; ++i) {
        const int tk = wv * 4 + i;
        const int r = tk >> 4, oct = tk & 15;
        const int grow = oy0 + py - 1 + r;         // input row; may be off-edge
        const bool ok = (unsigned)grow < 64u;
        const float* xp = x + ((size_t)(bi * NCI + oct * 8) * HIN + (ok ? grow : 0)) * HIN + lane;
        bf16x8 v;
        #pragma unroll
        for (int j = 0; j < 8; ++j) {
            float f = ok ? xp[(size_t)j * (HIN * HIN)] : 0.f;
            v[j] = (short)f32_to_bf16(f);
        }
        const int c = lane + 1;
        *(bf16x8*)&smem[((r * 66 + c) * 16 + (oct ^ (c & 15))) * 8] = v;
    }
    __syncthreads();

    f32x4 acc[2][4];
    #pragma unroll
    for (int i = 0; i < 2; ++i)
        #pragma unroll
        for (int j = 0; j < 4; ++j)
            acc[i][j] = (f32x4){0.f, 0.f, 0.f, 0.f};

    bf16x8 Abuf[3][2];
    auto loadA = [&](bf16x8* Ad, int kt) {
        const unsigned short* p = Aw6 + (((par * 64) + kt * 4 + cob) << 10) + lane * 8;
        Ad[0] = *(const bf16x8*)p;
        Ad[1] = *(const bf16x8*)(p + 512);
    };
    loadA(Abuf[0], 0);
    loadA(Abuf[1], 1);
    loadA(Abuf[2], 2);

    const int c0 = rl + pxw;
    #pragma unroll
    for (int kp = 0; kp < 16; ++kp) {            // fully unrolled: kp%3 static
        bf16x8* Ac = Abuf[kp % 3];
        const int ty = kp >> 3, tx = (kp >> 2) & 1, cq = kp & 3;
        __builtin_amdgcn_s_setprio(1);
        #pragma unroll
        for (int f = 0; f < 4; ++f) {
            const int c = c0 + f * 16 + tx;
            const int q = (cq * 4 + pl) ^ (c & 15);
            bf16x8 bfr = *(const bf16x8*)&smem[((ty * 66 + c) * 16 + q) * 8];
            #pragma unroll
            for (int fm = 0; fm < 2; ++fm)
                acc[fm][f] = __builtin_amdgcn_mfma_f32_16x16x32_bf16(
                    Ac[fm], bfr, acc[fm][f], 0, 0, 0);
        }
        __builtin_amdgcn_s_setprio(0);
        if (kp + 3 < 16) loadA(Abuf[kp % 3], kp + 3);
    }
    __syncthreads();   // all waves done reading B before lf overwrite

    // ---- epilogue: lf[64 co][132] overlay; 2 rounds of 64 co ----
    float* lf = (float*)smem;
    const int co_rd = tid >> 3;
    const int x16 = (tid & 7) * 16;
    const int yy = 2 * oy0 + py;
    #pragma unroll
    for (int b = 0; b < 2; ++b) {
        if ((cob >> 1) == b) {
            #pragma unroll
            for (int fm = 0; fm < 2; ++fm)
                #pragma unroll
                for (int fn = 0; fn < 4; ++fn) {
                    const int xx = 2 * (fn * 16 + rl) + pxw;
                    #pragma unroll
                    for (int j = 0; j < 4; ++j) {
                        const int co_l = (cob & 1) * 32 + fm * 16 + pl * 4 + j;
                        lf[co_l * 132 + xx] = acc[fm][fn][j];
                    }
                }
        }
        asm volatile("s_waitcnt lgkmcnt(0)" ::: "memory");
        __builtin_amdgcn_s_barrier();
        const int co_g = b * 64 + co_rd;
        const float bb = bv[co_g];
        float* op = out + (((size_t)(bi * NCO + co_g)) << 14) + yy * 128 + x16;
        const float* sp = lf + co_rd * 132 + x16;
        #pragma unroll
        for (int qq = 0; qq < 4; ++qq) {
            f32x4 v = *(const f32x4*)(sp + qq * 4);
            v[0] += bb; v[1] += bb; v[2] += bb; v[3] += bb;
            *(f32x4*)(op + qq * 4) = v;
        }
        if (b == 0) __builtin_amdgcn_s_barrier();
    }
}

// -------- fallback: flat Weff + direct-x kernel (round-1 proven) --------
__global__ void weff_flat_kernel(const float* __restrict__ W,
                                 unsigned short* __restrict__ Aw) {
    int idx = blockIdx.x * 256 + threadIdx.x;   // Aw[par][co][512]
    int par = idx >> 16;
    int co  = (idx >> 9) & 127;
    int k   = idx & 511;
    int tap = k >> 7, ci = k & 127;
    Aw[idx] = f32_to_bf16(weff_sum(W + (co * NCI + ci) * 9,
                                   par >> 1, par & 1, tap >> 1, tap & 1));
}

__global__ __launch_bounds__(256) void upconv_fb_kernel(
        const float* __restrict__ x, const unsigned short* __restrict__ Aw,
        const float* __restrict__ bv, float* __restrict__ out) {
    __shared__ __align__(16) unsigned short A_lds[128 * 32];
    __shared__ __align__(16) unsigned short B_lds[128 * 32];
    const int par = blockIdx.y, py = par >> 1, px = par & 1;
    const int s0 = blockIdx.x * 128;
    const int bimg = s0 >> 12;
    const int oy0 = (s0 >> 6) & 63;
    const int tid = threadIdx.x;
    const int lane = tid & 63, wave = tid >> 6;
    const int wm = wave >> 1, wn = wave & 1;
    const float* xb = x + bimg * (NCI * HIN * HIN);
    f32x4 acc[4][4];
    #pragma unroll
    for (int i = 0; i < 4; ++i)
        #pragma unroll
        for (int j = 0; j < 4; ++j)
            acc[i][j] = (f32x4){0.f, 0.f, 0.f, 0.f};
    for (int kt = 0; kt < 16; ++kt) {
        const int tap = kt >> 2, ci0 = (kt & 3) * 32;
        const int ty = tap >> 1, tx = tap & 1;
        #pragma unroll
        for (int i = 0; i < 2; ++i) {
            int c = i * 256 + tid;
            *(bf16x8*)(&A_lds[c * 8]) = *(const bf16x8*)(Aw +
                ((par * 128 + (c >> 2)) * 512 + kt * 32 + (c & 3) * 8));
        }
        #pragma unroll
        for (int i = 0; i < 2; ++i) {
            int tsk = i * 256 + tid;
            int n = tsk & 127, kg = tsk >> 7;
            int r = n >> 6, ox = n & 63;
            int row = oy0 + r - 1 + py + ty;
            int col = ox - 1 + px + tx;
            bool ok = (row >= 0) & (row < HIN) & (col >= 0) & (col < HIN);
            const float* xp = xb + (((ci0 + kg * 8) * HIN + row) * HIN + col);
            bf16x8 v;
            #pragma unroll
            for (int q = 0; q < 8; ++q) {
                float f = ok ? xp[q * (HIN * HIN)] : 0.f;
                v[q] = (short)f32_to_bf16(f);
            }
            *(bf16x8*)(&B_lds[n * 32 + kg * 8]) = v;
        }
        __syncthreads();
        const int seg = (lane >> 4) * 8, rl2 = lane & 15;
        bf16x8 af[4], bfr[4];
        #pragma unroll
        for (int f = 0; f < 4; ++f)
            af[f] = *(const bf16x8*)(&A_lds[(wm * 64 + f * 16 + rl2) * 32 + seg]);
        #pragma unroll
        for (int f = 0; f < 4; ++f)
            bfr[f] = *(const bf16x8*)(&B_lds[(wn * 64 + f * 16 + rl2) * 32 + seg]);
        #pragma unroll
        for (int fm = 0; fm < 4; ++fm)
            #pragma unroll
            for (int fn = 0; fn < 4; ++fn)
                acc[fm][fn] = __builtin_amdgcn_mfma_f32_16x16x32_bf16(
                    af[fm], bfr[fn], acc[fm][fn], 0, 0, 0);
        __syncthreads();
    }
    #pragma unroll
    for (int fm = 0; fm < 4; ++fm) {
        const int co_b = wm * 64 + fm * 16 + (lane >> 4) * 4;
        float bias4[4];
        #pragma unroll
        for (int j = 0; j < 4; ++j) bias4[j] = bv[co_b + j];
        #pragma unroll
        for (int fn = 0; fn < 4; ++fn) {
            int n = wn * 64 + fn * 16 + (lane & 15);
            int s = s0 + n;
            int ox = s & 63, oy = (s >> 6) & 63, bi2 = s >> 12;
            int yy = 2 * oy + py, xx = 2 * ox + px;
            float* op = out + ((size_t)bi2 * 128 * 128 * 128) + (size_t)yy * 128 + xx;
            #pragma unroll
            for (int j = 0; j < 4; ++j)
                op[(size_t)(co_b + j) * (128 * 128)] = acc[fm][fn][j] + bias4[j];
        }
    }
}

extern "C" void kernel_launch(void* const* d_in, const int* in_sizes, int n_in,
                              void* d_out, int out_size, void* d_ws, size_t ws_size,
                              hipStream_t stream) {
    const float* x  = (const float*)d_in[0];
    const float* W  = (const float*)d_in[1];
    const float* bv = (const float*)d_in[2];
    float* out = (float*)d_out;
    unsigned short* Aw = (unsigned short*)d_ws;               // 512 KB
    const size_t aw_bytes = (size_t)4 * 16 * 4 * 1024 * sizeof(unsigned short);

    if (ws_size >= aw_bytes) {
        weff6_kernel<<<1024, 256, 0, stream>>>(W, Aw);
        upconv14_kernel<<<1024, 512, 0, stream>>>(x, Aw, bv, out);
    } else {
        weff_flat_kernel<<<1024, 256, 0, stream>>>(W, Aw);
        upconv_fb_kernel<<<dim3(256, 4), 256, 0, stream>>>(x, Aw, bv, out);
    }
}

// Round 14
// 46.999 us; speedup vs baseline: 1.3889x; 1.0230x over previous
//
#include <hip/hip_runtime.h>
#include <stdint.h>

typedef short bf16x8 __attribute__((ext_vector_type(8)));
typedef float f32x4 __attribute__((ext_vector_type(4)));
typedef float f32x16 __attribute__((ext_vector_type(16)));

#define NCI 128
#define NCO 128
#define HIN 64
#define NB  8

__device__ __forceinline__ unsigned short f32_to_bf16(float f) {
    union { float f; uint32_t u; } v; v.f = f;
    return (unsigned short)((v.u + 0x7FFFu + ((v.u >> 16) & 1u)) >> 16);
}

// Effective 2x2-tap weight for parity (py,px), tap (ty,tx)
__device__ __forceinline__ float weff_sum(const float* wp, int py, int px, int ty, int tx) {
    float s = 0.f;
    #pragma unroll
    for (int ky = 0; ky < 3; ++ky) {
        bool iy = (py == 0) ? (ty == 0 ? (ky == 0) : (ky >= 1))
                            : (ty == 0 ? (ky <= 1) : (ky == 2));
        if (!iy) continue;
        #pragma unroll
        for (int kx = 0; kx < 3; ++kx) {
            bool ix = (px == 0) ? (tx == 0 ? (kx == 0) : (kx >= 1))
                                : (tx == 0 ? (kx <= 1) : (kx == 2));
            if (ix) s += wp[ky * 3 + kx];
        }
    }
    return s;
}

// Weff -> Aw7 for 32x32x16 fragments, wave-line-major (1KB frags):
//   offset = (((par*32 + s)*2 + cob)*2 + fm)*512 + lane*8 + e
//   content = Weff[par][co = cob*64 + fm*32 + (lane&31)]
//                  [k = s*16 + (lane>>5)*8 + e]          (512 KB total)
__global__ __launch_bounds__(256) void weff7_kernel(
        const float* __restrict__ W, unsigned short* __restrict__ Aw7) {
    int idx = blockIdx.x * 256 + threadIdx.x;     // 262144 total
    int e   = idx & 7;
    int ln  = (idx >> 3) & 63;
    int fm  = (idx >> 9) & 1;
    int cob = (idx >> 10) & 1;
    int s   = (idx >> 11) & 31;
    int par = idx >> 16;
    int co = cob * 64 + fm * 32 + (ln & 31);
    int k  = s * 16 + (ln >> 5) * 8 + e;
    int tap = k >> 7, ci = k & 127;
    Aw7[idx] = f32_to_bf16(weff_sum(W + (co * NCI + ci) * 9,
                                    par >> 1, par & 1, tap >> 1, tap & 1));
}

// Fused upsample-conv, 32x32x16 MFMA. Block = (bi, oy0, py), 256 thr = 4 waves
// (pxw x cob), wave = 64co x 64sp. Stage 2 input rows f32->bf16 swizzled LDS
// (33.8 KB) once; barrier-free 32-step K-loop: A 3-deep global(L2)->reg
// rotation, B from LDS, 4 MFMA/step; LDS-merged coalesced epilogue.
__global__ __launch_bounds__(256, 4) void upconv15_kernel(
        const float* __restrict__ x, const unsigned short* __restrict__ Aw7,
        const float* __restrict__ bv, float* __restrict__ out) {
    // LDS: [r 0..1][c 0..65][chunk q 0..15 of 8ci][16B]; store at q ^ (c&15).
    // Epilogue overlays as float[64][132] (exactly 33792 B).
    __shared__ __align__(16) unsigned short smem[16896];
    const int d = blockIdx.x;                 // 1024 blocks
    const int bi = d & 7;                     // XCD-local image
    const int py = (d >> 3) & 1;
    const int oy0 = d >> 4;                   // 0..63
    const int tid = threadIdx.x, lane = tid & 63, wv = tid >> 6;
    const int pxw = wv & 1, cob = wv >> 1;    // cob 0..1
    const int l31 = lane & 31, lh = lane >> 5;
    const int par = py * 2 + pxw;

    // ---- zero col-halo cells c = 0, 65 ----
    if (tid < 64) {
        int r = tid >> 5, cz = ((tid >> 4) & 1) * 65, q = tid & 15;
        *(bf16x8*)&smem[(((r * 66 + cz) << 4) + q) * 8] = (bf16x8){0,0,0,0,0,0,0,0};
    }
    // ---- stage interior: 32 tasks (r x ci-octet), 8 per wave; lane = col ----
    #pragma unroll
    for (int i = 0; i < 8; ++i) {
        const int tk = wv * 8 + i;
        const int r = tk >> 4, oct = tk & 15;
        const int grow = oy0 + py - 1 + r;
        const bool ok = (unsigned)grow < 64u;
        const float* xp = x + ((size_t)(bi * NCI + oct * 8) * HIN + (ok ? grow : 0)) * HIN + lane;
        bf16x8 v;
        #pragma unroll
        for (int j = 0; j < 8; ++j) {
            float f = ok ? xp[(size_t)j * (HIN * HIN)] : 0.f;
            v[j] = (short)f32_to_bf16(f);
        }
        const int c = lane + 1;
        *(bf16x8*)&smem[(((r * 66 + c) << 4) + (oct ^ (c & 15))) * 8] = v;
    }
    __syncthreads();

    f32x16 acc[2][2];
    #pragma unroll
    for (int i = 0; i < 2; ++i)
        #pragma unroll
        for (int j = 0; j < 2; ++j)
            #pragma unroll
            for (int q = 0; q < 16; ++q)
                acc[i][j][q] = 0.f;

    bf16x8 Abuf[3][2];
    auto loadA = [&](bf16x8* Ad, int s) {
        const unsigned short* p = Aw7 + (((par * 32 + s) * 2 + cob) << 10) + lane * 8;
        Ad[0] = *(const bf16x8*)p;
        Ad[1] = *(const bf16x8*)(p + 512);
    };
    loadA(Abuf[0], 0);
    loadA(Abuf[1], 1);
    loadA(Abuf[2], 2);

    #pragma unroll
    for (int s = 0; s < 32; ++s) {            // fully unrolled: s%3 static
        bf16x8* Ac = Abuf[s % 3];
        const int ty = s >> 4, tx = (s >> 3) & 1, qb = (s & 7) * 2;
        __builtin_amdgcn_s_setprio(1);
        #pragma unroll
        for (int fn = 0; fn < 2; ++fn) {
            const int c = l31 + fn * 32 + pxw + tx;
            const int q = (qb + lh) ^ (c & 15);
            bf16x8 bfr = *(const bf16x8*)&smem[(((ty * 66 + c) << 4) + q) * 8];
            #pragma unroll
            for (int fm = 0; fm < 2; ++fm)
                acc[fm][fn] = __builtin_amdgcn_mfma_f32_32x32x16_bf16(
                    Ac[fm], bfr, acc[fm][fn], 0, 0, 0);
        }
        __builtin_amdgcn_s_setprio(0);
        if (s + 3 < 32) loadA(Abuf[s % 3], s + 3);
    }
    __syncthreads();   // all waves done reading B before lf overwrite

    // ---- epilogue: lf[64 co][132] overlay; 2 rounds of 64 co ----
    // C/D layout (32x32): col = lane&31, row = (reg&3) + 8*(reg>>2) + 4*(lane>>5)
    float* lf = (float*)smem;
    const int co_rd = tid >> 2;
    const int x32 = (tid & 3) * 32;
    const int yy = 2 * oy0 + py;
    #pragma unroll
    for (int b = 0; b < 2; ++b) {
        if (cob == b) {
            #pragma unroll
            for (int fm = 0; fm < 2; ++fm)
                #pragma unroll
                for (int fn = 0; fn < 2; ++fn)
                    #pragma unroll
                    for (int j = 0; j < 16; ++j) {
                        const int row = (j & 3) + 8 * (j >> 2) + 4 * lh;
                        const int co_l = fm * 32 + row;
                        const int xx = 2 * (fn * 32 + l31) + pxw;
                        lf[co_l * 132 + xx] = acc[fm][fn][j];
                    }
        }
        __syncthreads();
        const int co_g = b * 64 + co_rd;
        const float bb = bv[co_g];
        float* op = out + (((size_t)(bi * NCO + co_g)) << 14) + yy * 128 + x32;
        const float* sp = lf + co_rd * 132 + x32;
        #pragma unroll
        for (int qq = 0; qq < 8; ++qq) {
            f32x4 v = *(const f32x4*)(sp + qq * 4);
            v[0] += bb; v[1] += bb; v[2] += bb; v[3] += bb;
            *(f32x4*)(op + qq * 4) = v;
        }
        if (b == 0) __syncthreads();
    }
}

// -------- fallback: flat Weff + direct-x kernel (round-1 proven) --------
__global__ void weff_flat_kernel(const float* __restrict__ W,
                                 unsigned short* __restrict__ Aw) {
    int idx = blockIdx.x * 256 + threadIdx.x;   // Aw[par][co][512]
    int par = idx >> 16;
    int co  = (idx >> 9) & 127;
    int k   = idx & 511;
    int tap = k >> 7, ci = k & 127;
    Aw[idx] = f32_to_bf16(weff_sum(W + (co * NCI + ci) * 9,
                                   par >> 1, par & 1, tap >> 1, tap & 1));
}

__global__ __launch_bounds__(256) void upconv_fb_kernel(
        const float* __restrict__ x, const unsigned short* __restrict__ Aw,
        const float* __restrict__ bv, float* __restrict__ out) {
    __shared__ __align__(16) unsigned short A_lds[128 * 32];
    __shared__ __align__(16) unsigned short B_lds[128 * 32];
    const int par = blockIdx.y, py = par >> 1, px = par & 1;
    const int s0 = blockIdx.x * 128;
    const int bimg = s0 >> 12;
    const int oy0 = (s0 >> 6) & 63;
    const int tid = threadIdx.x;
    const int lane = tid & 63, wave = tid >> 6;
    const int wm = wave >> 1, wn = wave & 1;
    const float* xb = x + bimg * (NCI * HIN * HIN);
    f32x4 acc[4][4];
    #pragma unroll
    for (int i = 0; i < 4; ++i)
        #pragma unroll
        for (int j = 0; j < 4; ++j)
            acc[i][j] = (f32x4){0.f, 0.f, 0.f, 0.f};
    for (int kt = 0; kt < 16; ++kt) {
        const int tap = kt >> 2, ci0 = (kt & 3) * 32;
        const int ty = tap >> 1, tx = tap & 1;
        #pragma unroll
        for (int i = 0; i < 2; ++i) {
            int c = i * 256 + tid;
            *(bf16x8*)(&A_lds[c * 8]) = *(const bf16x8*)(Aw +
                ((par * 128 + (c >> 2)) * 512 + kt * 32 + (c & 3) * 8));
        }
        #pragma unroll
        for (int i = 0; i < 2; ++i) {
            int tsk = i * 256 + tid;
            int n = tsk & 127, kg = tsk >> 7;
            int r = n >> 6, ox = n & 63;
            int row = oy0 + r - 1 + py + ty;
            int col = ox - 1 + px + tx;
            bool ok = (row >= 0) & (row < HIN) & (col >= 0) & (col < HIN);
            const float* xp = xb + (((ci0 + kg * 8) * HIN + row) * HIN + col);
            bf16x8 v;
            #pragma unroll
            for (int q = 0; q < 8; ++q) {
                float f = ok ? xp[q * (HIN * HIN)] : 0.f;
                v[q] = (short)f32_to_bf16(f);
            }
            *(bf16x8*)(&B_lds[n * 32 + kg * 8]) = v;
        }
        __syncthreads();
        const int seg = (lane >> 4) * 8, rl2 = lane & 15;
        bf16x8 af[4], bfr[4];
        #pragma unroll
        for (int f = 0; f < 4; ++f)
            af[f] = *(const bf16x8*)(&A_lds[(wm * 64 + f * 16 + rl2) * 32 + seg]);
        #pragma unroll
        for (int f = 0; f < 4; ++f)
            bfr[f] = *(const bf16x8*)(&B_lds[(wn * 64 + f * 16 + rl2) * 32 + seg]);
        #pragma unroll
        for (int fm = 0; fm < 4; ++fm)
            #pragma unroll
            for (int fn = 0; fn < 4; ++fn)
                acc[fm][fn] = __builtin_amdgcn_mfma_f32_16x16x32_bf16(
                    af[fm], bfr[fn], acc[fm][fn], 0, 0, 0);
        __syncthreads();
    }
    #pragma unroll
    for (int fm = 0; fm < 4; ++fm) {
        const int co_b = wm * 64 + fm * 16 + (lane >> 4) * 4;
        float bias4[4];
        #pragma unroll
        for (int j = 0; j < 4; ++j) bias4[j] = bv[co_b + j];
        #pragma unroll
        for (int fn = 0; fn < 4; ++fn) {
            int n = wn * 64 + fn * 16 + (lane & 15);
            int s = s0 + n;
            int ox = s & 63, oy = (s >> 6) & 63, bi2 = s >> 12;
            int yy = 2 * oy + py, xx = 2 * ox + px;
            float* op = out + ((size_t)bi2 * 128 * 128 * 128) + (size_t)yy * 128 + xx;
            #pragma unroll
            for (int j = 0; j < 4; ++j)
                op[(size_t)(co_b + j) * (128 * 128)] = acc[fm][fn][j] + bias4[j];
        }
    }
}

extern "C" void kernel_launch(void* const* d_in, const int* in_sizes, int n_in,
                              void* d_out, int out_size, void* d_ws, size_t ws_size,
                              hipStream_t stream) {
    const float* x  = (const float*)d_in[0];
    const float* W  = (const float*)d_in[1];
    const float* bv = (const float*)d_in[2];
    float* out = (float*)d_out;
    unsigned short* Aw = (unsigned short*)d_ws;               // 512 KB
    const size_t aw_bytes = (size_t)4 * 32 * 2 * 2 * 512 * sizeof(unsigned short);

    if (ws_size >= aw_bytes) {
        weff7_kernel<<<1024, 256, 0, stream>>>(W, Aw);
        upconv15_kernel<<<1024, 256, 0, stream>>>(x, Aw, bv, out);
    } else {
        weff_flat_kernel<<<1024, 256, 0, stream>>>(W, Aw);
        upconv_fb_kernel<<<dim3(256, 4), 256, 0, stream>>>(x, Aw, bv, out);
    }
}

// Round 15
// 41.395 us; speedup vs baseline: 1.5769x; 1.1354x over previous
//
#include <hip/hip_runtime.h>
#include <stdint.h>

typedef short bf16x8 __attribute__((ext_vector_type(8)));
typedef float f32x4 __attribute__((ext_vector_type(4)));
typedef float f32x16 __attribute__((ext_vector_type(16)));

#define NCI 128
#define NCO 128
#define HIN 64
#define HP  66
#define NB  8

__device__ __forceinline__ unsigned short f32_to_bf16(float f) {
    union { float f; uint32_t u; } v; v.f = f;
    return (unsigned short)((v.u + 0x7FFFu + ((v.u >> 16) & 1u)) >> 16);
}

__device__ __forceinline__ void gl_lds16(const void* g, void* l) {
    __builtin_amdgcn_global_load_lds(
        (const __attribute__((address_space(1))) unsigned int*)g,
        (__attribute__((address_space(3))) unsigned int*)l, 16, 0, 0);
}

// Effective 2x2-tap weight for parity (py,px), tap (ty,tx)
__device__ __forceinline__ float weff_sum(const float* wp, int py, int px, int ty, int tx) {
    float s = 0.f;
    #pragma unroll
    for (int ky = 0; ky < 3; ++ky) {
        bool iy = (py == 0) ? (ty == 0 ? (ky == 0) : (ky >= 1))
                            : (ty == 0 ? (ky <= 1) : (ky == 2));
        if (!iy) continue;
        #pragma unroll
        for (int kx = 0; kx < 3; ++kx) {
            bool ix = (px == 0) ? (tx == 0 ? (kx == 0) : (kx >= 1))
                                : (tx == 0 ? (kx <= 1) : (kx == 2));
            if (ix) s += wp[ky * 3 + kx];
        }
    }
    return s;
}

// ---- fused prologue ----
// blocks [0,1024): Weff -> Aw8 in A-LDS-image layout (per (par,coh): 64 KB linear):
//   idx bits: e(0-2) l(3-8) fm(9) s(10-14) coh(15) par(16-17)
//   content = Weff[par][co = coh*64 + fm*32 + (l&31)][k = s*16 + (l>>5)*8 + e]
// blocks [1024,1552): x -> xq [8][4][66][66][32] bf16 (ci-chunked NHWC, halo incl).
__global__ __launch_bounds__(256) void prep_kernel(
        const float* __restrict__ W, const float* __restrict__ x,
        unsigned short* __restrict__ Aw8, unsigned short* __restrict__ xq) {
    if (blockIdx.x < 1024) {
        int idx = blockIdx.x * 256 + threadIdx.x;     // 262144 total
        int e   = idx & 7;
        int l   = (idx >> 3) & 63;
        int fm  = (idx >> 9) & 1;
        int s   = (idx >> 10) & 31;
        int coh = (idx >> 15) & 1;
        int par = idx >> 16;
        int co = coh * 64 + fm * 32 + (l & 31);
        int k  = s * 16 + (l >> 5) * 8 + e;
        int tap = k >> 7, ci = k & 127;
        Aw8[idx] = f32_to_bf16(weff_sum(W + (co * NCI + ci) * 9,
                                        par >> 1, par & 1, tap >> 1, tap & 1));
    } else {
        const int bb = blockIdx.x - 1024;             // 528 blocks
        const int b = bb / HP, hp = bb % HP;
        const int t = threadIdx.x;
        if (hp == 0 || hp == HP - 1) {
            bf16x8 z = (bf16x8){0, 0, 0, 0, 0, 0, 0, 0};
            for (int i = t; i < 4 * HP * 4; i += 256) {
                int g = i / (HP * 4), rem = i % (HP * 4);
                unsigned short* dst = xq +
                    ((((size_t)(b * 4 + g) * HP + hp) * HP) << 5) + rem * 8;
                *(bf16x8*)dst = z;
            }
            return;
        }
        const int h = hp - 1;
        if (t < 32) {                                  // column halo wp = 0, 65
            bf16x8 z = (bf16x8){0, 0, 0, 0, 0, 0, 0, 0};
            int g = t >> 3, wpc = ((t >> 2) & 1) * (HP - 1), q = t & 3;
            unsigned short* dst = xq +
                ((((size_t)(b * 4 + g) * HP + hp) * HP + wpc) << 5) + q * 8;
            *(bf16x8*)dst = z;
        }
        const int w = t & 63, g = t >> 6;
        const float* src = x + ((size_t)(b * NCI + g * 32) * (HIN * HIN)) + h * HIN + w;
        unsigned short* dst = xq +
            ((((size_t)(b * 4 + g) * HP + hp) * HP + (w + 1)) << 5);
        #pragma unroll
        for (int q = 0; q < 4; ++q) {
            bf16x8 v;
            #pragma unroll
            for (int j = 0; j < 8; ++j)
                v[j] = (short)f32_to_bf16(src[(size_t)(q * 8 + j) * (HIN * HIN)]);
            *(bf16x8*)(dst + q * 8) = v;
        }
    }
}

// Main GEMM: ZERO global loads in the K-loop. Per block, stage once via bulk
// gl_lds: A-half (64co x 512K = 64 KB, frag-major) + B 5-row window (84.5 KB,
// XOR-swizzled) -> 150 KB LDS. Block = (bi, py, px, coh, ys strip of 4 oy).
// 8 waves = oy(4) x sp-half(2); wave = 64co x 32sp, 32 steps x {2 A-LDS-reads,
// 1 B-LDS-read, 2 mfma 32x32x16}. Direct stores (px-partner block d^16 is
// co-resident on the same XCD for L2 write-merge).
__global__ __launch_bounds__(512, 2) void upconv16_kernel(
        const unsigned short* __restrict__ xq, const unsigned short* __restrict__ Aw8,
        const float* __restrict__ bv, float* __restrict__ out) {
    __shared__ __align__(16) unsigned short A_lds[32768];   //  64 KB
    __shared__ __align__(16) unsigned short B_lds[42240];   //  82.5 KB
    const int d = blockIdx.x;                 // 1024 blocks
    const int bi  = d & 7;                    // XCD-local image
    const int py  = (d >> 3) & 1;
    const int px  = (d >> 4) & 1;             // partner d^16 co-resident
    const int coh = (d >> 5) & 1;
    const int ys  = d >> 6;                   // 0..15 (strip of 4 oy rows)
    const int tid = threadIdx.x, lane = tid & 63, wv = tid >> 6;
    const int sph = wv & 1, ol = wv >> 1;     // sp-half, oy-local
    const int l31 = lane & 31, lh = lane >> 5;
    const int par = py * 2 + px;

    // ---- stage A: 4096 x 16B linear copy ----
    const unsigned short* Ag = Aw8 + (((size_t)(par * 2 + coh)) << 15);
    #pragma unroll
    for (int i = 0; i < 8; ++i) {
        const int u = i * 512 + tid;
        gl_lds16(Ag + u * 8, &A_lds[u * 8]);
    }
    // ---- stage B: 5280 x 16B; slot u = ((r*66+c)*16 + qs), qs = q ^ (c&15) ----
    #pragma unroll
    for (int i = 0; i < 11; ++i) {
        const int u = i * 512 + tid;
        if (u < 5280) {
            const int qs = u & 15, cell = u >> 4;
            const int r = cell / 66, c = cell - r * 66;
            const int q = qs ^ (c & 15);
            const int hp = ys * 4 + py + r;          // 0..65, halo in xq
            const unsigned short* gb = xq +
                ((((size_t)(bi * 4 + (q >> 2)) * HP + hp) * HP + c) << 5) + (q & 3) * 8;
            gl_lds16(gb, &B_lds[u * 8]);
        }
    }
    asm volatile("s_waitcnt vmcnt(0)" ::: "memory");
    __builtin_amdgcn_s_barrier();

    f32x16 acc[2];
    #pragma unroll
    for (int i = 0; i < 2; ++i)
        #pragma unroll
        for (int q = 0; q < 16; ++q)
            acc[i][q] = 0.f;

    // ---- K-loop: all-LDS ----
    #pragma unroll
    for (int s = 0; s < 32; ++s) {
        const int ty = s >> 4, tx = (s >> 3) & 1;
        const int q = (s & 7) * 2 + lh;
        const int r = ol + ty;
        const int c = sph * 32 + l31 + px + tx;
        const int qs = q ^ (c & 15);
        const bf16x8 bfr = *(const bf16x8*)&B_lds[(((r * 66 + c) << 4) + qs) * 8];
        const unsigned short* ap = &A_lds[(s << 10) + lane * 8];
        __builtin_amdgcn_s_setprio(1);
        acc[0] = __builtin_amdgcn_mfma_f32_32x32x16_bf16(
            *(const bf16x8*)ap, bfr, acc[0], 0, 0, 0);
        acc[1] = __builtin_amdgcn_mfma_f32_32x32x16_bf16(
            *(const bf16x8*)(ap + 512), bfr, acc[1], 0, 0, 0);
        __builtin_amdgcn_s_setprio(0);
    }

    // ---- epilogue: direct stores. C/D 32x32: col = l31 (sp), row = (j&3)+8*(j>>2)+4*lh
    const int yy = 2 * (ys * 4 + ol) + py;
    const int xx = 2 * (sph * 32 + l31) + px;
    #pragma unroll
    for (int fm = 0; fm < 2; ++fm) {
        #pragma unroll
        for (int j = 0; j < 16; ++j) {
            const int row = (j & 3) + 8 * (j >> 2) + 4 * lh;
            const int co = coh * 64 + fm * 32 + row;
            out[(((size_t)(bi * NCO + co)) << 14) + yy * 128 + xx] = acc[fm][j] + bv[co];
        }
    }
}

// -------- fallback: flat Weff + direct-x kernel (round-1 proven) --------
__global__ void weff_flat_kernel(const float* __restrict__ W,
                                 unsigned short* __restrict__ Aw) {
    int idx = blockIdx.x * 256 + threadIdx.x;   // Aw[par][co][512]
    int par = idx >> 16;
    int co  = (idx >> 9) & 127;
    int k   = idx & 511;
    int tap = k >> 7, ci = k & 127;
    Aw[idx] = f32_to_bf16(weff_sum(W + (co * NCI + ci) * 9,
                                   par >> 1, par & 1, tap >> 1, tap & 1));
}

__global__ __launch_bounds__(256) void upconv_fb_kernel(
        const float* __restrict__ x, const unsigned short* __restrict__ Aw,
        const float* __restrict__ bv, float* __restrict__ out) {
    __shared__ __align__(16) unsigned short A_lds[128 * 32];
    __shared__ __align__(16) unsigned short B_lds[128 * 32];
    const int par = blockIdx.y, py = par >> 1, px = par & 1;
    const int s0 = blockIdx.x * 128;
    const int bimg = s0 >> 12;
    const int oy0 = (s0 >> 6) & 63;
    const int tid = threadIdx.x;
    const int lane = tid & 63, wave = tid >> 6;
    const int wm = wave >> 1, wn = wave & 1;
    const float* xb = x + bimg * (NCI * HIN * HIN);
    f32x4 acc[4][4];
    #pragma unroll
    for (int i = 0; i < 4; ++i)
        #pragma unroll
        for (int j = 0; j < 4; ++j)
            acc[i][j] = (f32x4){0.f, 0.f, 0.f, 0.f};
    for (int kt = 0; kt < 16; ++kt) {
        const int tap = kt >> 2, ci0 = (kt & 3) * 32;
        const int ty = tap >> 1, tx = tap & 1;
        #pragma unroll
        for (int i = 0; i < 2; ++i) {
            int c = i * 256 + tid;
            *(bf16x8*)(&A_lds[c * 8]) = *(const bf16x8*)(Aw +
                ((par * 128 + (c >> 2)) * 512 + kt * 32 + (c & 3) * 8));
        }
        #pragma unroll
        for (int i = 0; i < 2; ++i) {
            int tsk = i * 256 + tid;
            int n = tsk & 127, kg = tsk >> 7;
            int r = n >> 6, ox = n & 63;
            int row = oy0 + r - 1 + py + ty;
            int col = ox - 1 + px + tx;
            bool ok = (row >= 0) & (row < HIN) & (col >= 0) & (col < HIN);
            const float* xp = xb + (((ci0 + kg * 8) * HIN + row) * HIN + col);
            bf16x8 v;
            #pragma unroll
            for (int q = 0; q < 8; ++q) {
                float f = ok ? xp[q * (HIN * HIN)] : 0.f;
                v[q] = (short)f32_to_bf16(f);
            }
            *(bf16x8*)(&B_lds[n * 32 + kg * 8]) = v;
        }
        __syncthreads();
        const int seg = (lane >> 4) * 8, rl2 = lane & 15;
        bf16x8 af[4], bfr[4];
        #pragma unroll
        for (int f = 0; f < 4; ++f)
            af[f] = *(const bf16x8*)(&A_lds[(wm * 64 + f * 16 + rl2) * 32 + seg]);
        #pragma unroll
        for (int f = 0; f < 4; ++f)
            bfr[f] = *(const bf16x8*)(&B_lds[(wn * 64 + f * 16 + rl2) * 32 + seg]);
        #pragma unroll
        for (int fm = 0; fm < 4; ++fm)
            #pragma unroll
            for (int fn = 0; fn < 4; ++fn)
                acc[fm][fn] = __builtin_amdgcn_mfma_f32_16x16x32_bf16(
                    af[fm], bfr[fn], acc[fm][fn], 0, 0, 0);
        __syncthreads();
    }
    #pragma unroll
    for (int fm = 0; fm < 4; ++fm) {
        const int co_b = wm * 64 + fm * 16 + (lane >> 4) * 4;
        float bias4[4];
        #pragma unroll
        for (int j = 0; j < 4; ++j) bias4[j] = bv[co_b + j];
        #pragma unroll
        for (int fn = 0; fn < 4; ++fn) {
            int n = wn * 64 + fn * 16 + (lane & 15);
            int s = s0 + n;
            int ox = s & 63, oy = (s >> 6) & 63, bi2 = s >> 12;
            int yy = 2 * oy + py, xx = 2 * ox + px;
            float* op = out + ((size_t)bi2 * 128 * 128 * 128) + (size_t)yy * 128 + xx;
            #pragma unroll
            for (int j = 0; j < 4; ++j)
                op[(size_t)(co_b + j) * (128 * 128)] = acc[fm][fn][j] + bias4[j];
        }
    }
}

extern "C" void kernel_launch(void* const* d_in, const int* in_sizes, int n_in,
                              void* d_out, int out_size, void* d_ws, size_t ws_size,
                              hipStream_t stream) {
    const float* x  = (const float*)d_in[0];
    const float* W  = (const float*)d_in[1];
    const float* bv = (const float*)d_in[2];
    float* out = (float*)d_out;
    unsigned short* Aw = (unsigned short*)d_ws;               // 512 KB
    const size_t aw_bytes = (size_t)4 * 2 * 32 * 2 * 512 * sizeof(unsigned short);
    const size_t xq_bytes = (size_t)NB * 4 * HP * HP * 32 * sizeof(unsigned short);

    if (ws_size >= aw_bytes + xq_bytes) {
        unsigned short* xq = (unsigned short*)((char*)d_ws + aw_bytes);
        prep_kernel<<<1024 + NB * HP, 256, 0, stream>>>(W, x, Aw, xq);
        upconv16_kernel<<<1024, 512, 0, stream>>>(xq, Aw, bv, out);
    } else {
        weff_flat_kernel<<<1024, 256, 0, stream>>>(W, Aw);
        upconv_fb_kernel<<<dim3(256, 4), 256, 0, stream>>>(x, Aw, bv, out);
    }
}

// Round 16
// 41.241 us; speedup vs baseline: 1.5828x; 1.0037x over previous
//
#include <hip/hip_runtime.h>
#include <stdint.h>

typedef short bf16x8 __attribute__((ext_vector_type(8)));
typedef float f32x4 __attribute__((ext_vector_type(4)));
typedef float f32x16 __attribute__((ext_vector_type(16)));

#define NCI 128
#define NCO 128
#define HIN 64
#define NB  8

__device__ __forceinline__ unsigned short f32_to_bf16(float f) {
    union { float f; uint32_t u; } v; v.f = f;
    return (unsigned short)((v.u + 0x7FFFu + ((v.u >> 16) & 1u)) >> 16);
}

__device__ __forceinline__ void gl_lds16(const void* g, void* l) {
    __builtin_amdgcn_global_load_lds(
        (const __attribute__((address_space(1))) unsigned int*)g,
        (__attribute__((address_space(3))) unsigned int*)l, 16, 0, 0);
}

// Effective 2x2-tap weight for parity (py,px), tap (ty,tx)
__device__ __forceinline__ float weff_sum(const float* wp, int py, int px, int ty, int tx) {
    float s = 0.f;
    #pragma unroll
    for (int ky = 0; ky < 3; ++ky) {
        bool iy = (py == 0) ? (ty == 0 ? (ky == 0) : (ky >= 1))
                            : (ty == 0 ? (ky <= 1) : (ky == 2));
        if (!iy) continue;
        #pragma unroll
        for (int kx = 0; kx < 3; ++kx) {
            bool ix = (px == 0) ? (tx == 0 ? (kx == 0) : (kx >= 1))
                                : (tx == 0 ? (kx <= 1) : (kx == 2));
            if (ix) s += wp[ky * 3 + kx];
        }
    }
    return s;
}

// ---- fused prologue ----
// blocks [0,1024): Weff -> Aw9 (1KB wave-line frags for 32x32x16):
//   offset = (((par*2+coh)*32 + s)*1024) + fm*512 + lane*8 + e
//   content = Weff[par][co = coh*64 + fm*32 + (lane&31)][k = s*16 + (lane>>5)*8 + e]
// blocks [1024,1552): x -> xq [8][4 g][66 hp][64 w][32 ci] bf16 (row halo only).
__global__ __launch_bounds__(256) void prep_kernel(
        const float* __restrict__ W, const float* __restrict__ x,
        unsigned short* __restrict__ Aw9, unsigned short* __restrict__ xq) {
    if (blockIdx.x < 1024) {
        int idx = blockIdx.x * 256 + threadIdx.x;     // 262144 total
        int e   = idx & 7;
        int l   = (idx >> 3) & 63;
        int fm  = (idx >> 9) & 1;
        int s   = (idx >> 10) & 31;
        int coh = (idx >> 15) & 1;
        int par = idx >> 16;
        int co = coh * 64 + fm * 32 + (l & 31);
        int k  = s * 16 + (l >> 5) * 8 + e;
        int tap = k >> 7, ci = k & 127;
        Aw9[idx] = f32_to_bf16(weff_sum(W + (co * NCI + ci) * 9,
                                        par >> 1, par & 1, tap >> 1, tap & 1));
    } else {
        const int bb = blockIdx.x - 1024;             // 528 blocks (8 b x 66 hp)
        const int b = bb / 66, hp = bb % 66;
        const int t = threadIdx.x;
        unsigned short* rowp = xq + ((((size_t)b * 4) * 66 + hp) * 64) * 32;
        if (hp == 0 || hp == 65) {                    // zero halo rows, all 4 g
            bf16x8 z = (bf16x8){0, 0, 0, 0, 0, 0, 0, 0};
            for (int i = t; i < 1024; i += 256) {     // 4g x 64w x 4q
                int g = i >> 8, rem = i & 255;
                int w = rem >> 2, q = rem & 3;
                *(bf16x8*)(xq + (((((size_t)(b * 4 + g)) * 66 + hp) * 64 + w) << 5) + q * 8) = z;
            }
            return;
        }
        const int h = hp - 1;
        const int w = t & 63, g = t >> 6;
        const float* src = x + ((size_t)(b * NCI + g * 32) * (HIN * HIN)) + h * HIN + w;
        unsigned short* dst = xq + (((((size_t)(b * 4 + g)) * 66 + hp) * 64 + w) << 5);
        #pragma unroll
        for (int q = 0; q < 4; ++q) {
            bf16x8 v;
            #pragma unroll
            for (int j = 0; j < 8; ++j)
                v[j] = (short)f32_to_bf16(src[(size_t)(q * 8 + j) * (HIN * HIN)]);
            *(bf16x8*)(dst + q * 8) = v;
        }
    }
}

// Main GEMM: B-only LDS (5 rows x 64 cols x 256B = 80 KB exactly -> 2 blocks/CU,
// cross-block stage/compute overlap). A streams L2->reg 3-deep (1KB wave-lines).
// Block = (bi, py, px, coh, ys strip of 4 oy); 256 thr = 4 waves (ol = oy-local);
// wave = 64co x 64sp, 32 steps x {2 A-reads(global), 2 B-reads(LDS), 4 MFMA
// 32x32x16}. Col-halo handled by per-lane select (no LDS halo col).
__global__ __launch_bounds__(256, 2) void upconv17_kernel(
        const unsigned short* __restrict__ xq, const unsigned short* __restrict__ Aw9,
        const float* __restrict__ bv, float* __restrict__ out) {
    __shared__ __align__(16) unsigned short B_lds[40960];   // 81920 B exactly
    const int d = blockIdx.x;                 // 1024 blocks
    const int bi  = d & 7;                    // XCD-local image
    const int py  = (d >> 3) & 1;
    const int px  = (d >> 4) & 1;             // partner d^16 on same XCD
    const int coh = (d >> 5) & 1;
    const int ys  = d >> 6;                   // 0..15
    const int tid = threadIdx.x, lane = tid & 63, ol = tid >> 6;
    const int l31 = lane & 31, lh = lane >> 5;
    const int par = py * 2 + px;

    // ---- stage B window: 5120 x 16B; u -> (cell = u>>4, qs = u&15),
    //      cell = r*64 + w; source chunk q = qs ^ (w&15)  (rule #21) ----
    #pragma unroll
    for (int i = 0; i < 20; ++i) {
        const int u = i * 256 + tid;
        const int qs = u & 15, cell = u >> 4;
        const int r = cell >> 6, w = cell & 63;
        const int q = qs ^ (w & 15);
        const int hp = ys * 4 + py + r;       // 0..65 (row halo in xq)
        const unsigned short* gb = xq +
            (((((size_t)(bi * 4 + (q >> 2))) * 66 + hp) * 64 + w) << 5) + (q & 3) * 8;
        gl_lds16(gb, &B_lds[u * 8]);
    }

    const unsigned short* Ag = Aw9 + (((size_t)(par * 2 + coh)) << 15);
    bf16x8 Abuf[3][2];
    auto loadA = [&](bf16x8* Ad, int s) {
        const unsigned short* p = Ag + (s << 10) + lane * 8;
        Ad[0] = *(const bf16x8*)p;
        Ad[1] = *(const bf16x8*)(p + 512);
    };
    loadA(Abuf[0], 0);
    loadA(Abuf[1], 1);
    loadA(Abuf[2], 2);
    asm volatile("s_waitcnt vmcnt(0)" ::: "memory");
    __builtin_amdgcn_s_barrier();

    f32x16 acc[2][2];
    #pragma unroll
    for (int i = 0; i < 2; ++i)
        #pragma unroll
        for (int j = 0; j < 2; ++j)
            #pragma unroll
            for (int q = 0; q < 16; ++q)
                acc[i][j][q] = 0.f;

    #pragma unroll
    for (int s = 0; s < 32; ++s) {            // fully unrolled: s%3 static
        bf16x8* Ac = Abuf[s % 3];
        const int ty = s >> 4, tx = (s >> 3) & 1;
        const int q = (s & 7) * 2 + lh;
        const int r = ol + ty;                // 0..4
        __builtin_amdgcn_s_setprio(1);
        #pragma unroll
        for (int fn = 0; fn < 2; ++fn) {
            const int wr = fn * 32 + l31 + px + tx - 1;
            const bool valid = (unsigned)wr < 64u;
            const int w = valid ? wr : 0;
            const int qs = q ^ (w & 15);
            bf16x8 bfr = *(const bf16x8*)&B_lds[(((r << 6) + w) * 16 + qs) * 8];
            bfr = valid ? bfr : (bf16x8){0, 0, 0, 0, 0, 0, 0, 0};
            #pragma unroll
            for (int fm = 0; fm < 2; ++fm)
                acc[fm][fn] = __builtin_amdgcn_mfma_f32_32x32x16_bf16(
                    Ac[fm], bfr, acc[fm][fn], 0, 0, 0);
        }
        __builtin_amdgcn_s_setprio(0);
        if (s + 3 < 32) loadA(Abuf[s % 3], s + 3);
    }

    // ---- epilogue: direct stores; partner px-block merges in L2.
    // C/D 32x32: col = l31 (sp), row = (j&3) + 8*(j>>2) + 4*lh (co)
    const int yy = 2 * (ys * 4 + ol) + py;
    #pragma unroll
    for (int fm = 0; fm < 2; ++fm) {
        #pragma unroll
        for (int fn = 0; fn < 2; ++fn) {
            const int xx = 2 * (fn * 32 + l31) + px;
            #pragma unroll
            for (int j = 0; j < 16; ++j) {
                const int row = (j & 3) + 8 * (j >> 2) + 4 * lh;
                const int co = coh * 64 + fm * 32 + row;
                out[(((size_t)(bi * NCO + co)) << 14) + yy * 128 + xx] =
                    acc[fm][fn][j] + bv[co];
            }
        }
    }
}

// -------- fallback: flat Weff + direct-x kernel (round-1 proven) --------
__global__ void weff_flat_kernel(const float* __restrict__ W,
                                 unsigned short* __restrict__ Aw) {
    int idx = blockIdx.x * 256 + threadIdx.x;   // Aw[par][co][512]
    int par = idx >> 16;
    int co  = (idx >> 9) & 127;
    int k   = idx & 511;
    int tap = k >> 7, ci = k & 127;
    Aw[idx] = f32_to_bf16(weff_sum(W + (co * NCI + ci) * 9,
                                   par >> 1, par & 1, tap >> 1, tap & 1));
}

__global__ __launch_bounds__(256) void upconv_fb_kernel(
        const float* __restrict__ x, const unsigned short* __restrict__ Aw,
        const float* __restrict__ bv, float* __restrict__ out) {
    __shared__ __align__(16) unsigned short A_lds[128 * 32];
    __shared__ __align__(16) unsigned short B_lds[128 * 32];
    const int par = blockIdx.y, py = par >> 1, px = par & 1;
    const int s0 = blockIdx.x * 128;
    const int bimg = s0 >> 12;
    const int oy0 = (s0 >> 6) & 63;
    const int tid = threadIdx.x;
    const int lane = tid & 63, wave = tid >> 6;
    const int wm = wave >> 1, wn = wave & 1;
    const float* xb = x + bimg * (NCI * HIN * HIN);
    f32x4 acc[4][4];
    #pragma unroll
    for (int i = 0; i < 4; ++i)
        #pragma unroll
        for (int j = 0; j < 4; ++j)
            acc[i][j] = (f32x4){0.f, 0.f, 0.f, 0.f};
    for (int kt = 0; kt < 16; ++kt) {
        const int tap = kt >> 2, ci0 = (kt & 3) * 32;
        const int ty = tap >> 1, tx = tap & 1;
        #pragma unroll
        for (int i = 0; i < 2; ++i) {
            int c = i * 256 + tid;
            *(bf16x8*)(&A_lds[c * 8]) = *(const bf16x8*)(Aw +
                ((par * 128 + (c >> 2)) * 512 + kt * 32 + (c & 3) * 8));
        }
        #pragma unroll
        for (int i = 0; i < 2; ++i) {
            int tsk = i * 256 + tid;
            int n = tsk & 127, kg = tsk >> 7;
            int r = n >> 6, ox = n & 63;
            int row = oy0 + r - 1 + py + ty;
            int col = ox - 1 + px + tx;
            bool ok = (row >= 0) & (row < HIN) & (col >= 0) & (col < HIN);
            const float* xp = xb + (((ci0 + kg * 8) * HIN + row) * HIN + col);
            bf16x8 v;
            #pragma unroll
            for (int q = 0; q < 8; ++q) {
                float f = ok ? xp[q * (HIN * HIN)] : 0.f;
                v[q] = (short)f32_to_bf16(f);
            }
            *(bf16x8*)(&B_lds[n * 32 + kg * 8]) = v;
        }
        __syncthreads();
        const int seg = (lane >> 4) * 8, rl2 = lane & 15;
        bf16x8 af[4], bfr[4];
        #pragma unroll
        for (int f = 0; f < 4; ++f)
            af[f] = *(const bf16x8*)(&A_lds[(wm * 64 + f * 16 + rl2) * 32 + seg]);
        #pragma unroll
        for (int f = 0; f < 4; ++f)
            bfr[f] = *(const bf16x8*)(&B_lds[(wn * 64 + f * 16 + rl2) * 32 + seg]);
        #pragma unroll
        for (int fm = 0; fm < 4; ++fm)
            #pragma unroll
            for (int fn = 0; fn < 4; ++fn)
                acc[fm][fn] = __builtin_amdgcn_mfma_f32_16x16x32_bf16(
                    af[fm], bfr[fn], acc[fm][fn], 0, 0, 0);
        __syncthreads();
    }
    #pragma unroll
    for (int fm = 0; fm < 4; ++fm) {
        const int co_b = wm * 64 + fm * 16 + (lane >> 4) * 4;
        float bias4[4];
        #pragma unroll
        for (int j = 0; j < 4; ++j) bias4[j] = bv[co_b + j];
        #pragma unroll
        for (int fn = 0; fn < 4; ++fn) {
            int n = wn * 64 + fn * 16 + (lane & 15);
            int s = s0 + n;
            int ox = s & 63, oy = (s >> 6) & 63, bi2 = s >> 12;
            int yy = 2 * oy + py, xx = 2 * ox + px;
            float* op = out + ((size_t)bi2 * 128 * 128 * 128) + (size_t)yy * 128 + xx;
            #pragma unroll
            for (int j = 0; j < 4; ++j)
                op[(size_t)(co_b + j) * (128 * 128)] = acc[fm][fn][j] + bias4[j];
        }
    }
}

extern "C" void kernel_launch(void* const* d_in, const int* in_sizes, int n_in,
                              void* d_out, int out_size, void* d_ws, size_t ws_size,
                              hipStream_t stream) {
    const float* x  = (const float*)d_in[0];
    const float* W  = (const float*)d_in[1];
    const float* bv = (const float*)d_in[2];
    float* out = (float*)d_out;
    unsigned short* Aw = (unsigned short*)d_ws;               // 512 KB
    const size_t aw_bytes = (size_t)4 * 2 * 32 * 2 * 512 * sizeof(unsigned short);
    const size_t xq_bytes = (size_t)NB * 4 * 66 * 64 * 32 * sizeof(unsigned short);

    if (ws_size >= aw_bytes + xq_bytes) {
        unsigned short* xq = (unsigned short*)((char*)d_ws + aw_bytes);
        prep_kernel<<<1024 + 528, 256, 0, stream>>>(W, x, Aw, xq);
        upconv17_kernel<<<1024, 256, 0, stream>>>(xq, Aw, bv, out);
    } else {
        weff_flat_kernel<<<1024, 256, 0, stream>>>(W, Aw);
        upconv_fb_kernel<<<dim3(256, 4), 256, 0, stream>>>(x, Aw, bv, out);
    }
}